// Round 8
// baseline (671.770 us; speedup 1.0000x reference)
//
#include <hip/hip_runtime.h>

typedef unsigned short u16;
typedef __attribute__((ext_vector_type(4))) unsigned short u16x4;
typedef __attribute__((ext_vector_type(8))) unsigned short u16x8;
typedef __attribute__((ext_vector_type(4))) float f32x4;
typedef __attribute__((ext_vector_type(8))) __bf16 b16x8;

__device__ __forceinline__ float bf2f(u16 u) {
  unsigned x = ((unsigned)u) << 16;
  return __builtin_bit_cast(float, x);
}
__device__ __forceinline__ u16 f2bf(float f) {
  unsigned u = __builtin_bit_cast(unsigned, f);
  u += 0x7fffu + ((u >> 16) & 1u);
  return (u16)(u >> 16);
}
__device__ __forceinline__ f32x4 MFMA(u16x8 a, u16x8 b, f32x4 c) {
  return __builtin_amdgcn_mfma_f32_16x16x32_bf16(
      __builtin_bit_cast(b16x8, a), __builtin_bit_cast(b16x8, b), c, 0, 0, 0);
}
__device__ __forceinline__ u16x8 ldApk(const u16* __restrict__ Apk, int Kdiv8, int rb, int ks, int l) {
  int kb = (ks >> 3) + (l >> 4);
  return *(const u16x8*)(Apk + (((size_t)(rb * Kdiv8 + kb)) << 7) + ((l & 15) << 3));
}
__device__ __forceinline__ u16x8 ldsB(const char* base, int rowB, int e, int kbyte) {
  return *(const u16x8*)(base + e * rowB + (kbyte ^ ((e & 7) << 4)));
}

// wave computes 32 out rows (rb0=2w), 32 cols (edges 0..31 relative to Bb base)
__device__ __forceinline__ void gemm2x2(const u16* __restrict__ Apk, const char* Bb,
                                        int K, int rowB, int w, int l, f32x4 acc[2][2]) {
  int Kd8 = K >> 3;
  int rb0 = w * 2;
  for (int ks = 0; ks < K; ks += 32) {
    u16x8 a0 = ldApk(Apk, Kd8, rb0, ks, l);
    u16x8 a1 = ldApk(Apk, Kd8, rb0 + 1, ks, l);
    int kbyte = (ks + ((l >> 4) << 3)) << 1;
    u16x8 b0 = ldsB(Bb, rowB, l & 15, kbyte);
    u16x8 b1 = ldsB(Bb, rowB, 16 + (l & 15), kbyte);
    acc[0][0] = MFMA(a0, b0, acc[0][0]);
    acc[0][1] = MFMA(a0, b1, acc[0][1]);
    acc[1][0] = MFMA(a1, b0, acc[1][0]);
    acc[1][1] = MFMA(a1, b1, acc[1][1]);
  }
}

__device__ __forceinline__ void tanh_to_H(char* hb, int w, int l, f32x4 acc[2][2]) {
  for (int mi = 0; mi < 2; ++mi)
    for (int ni = 0; ni < 2; ++ni) {
      int e = 16 * ni + (l & 15);
      int cb = w * 32 + 16 * mi + ((l >> 4) << 2);
      u16x4 hv;
      for (int r = 0; r < 4; ++r) hv[r] = f2bf(tanhf(acc[mi][ni][r]));
      *(u16x4*)(hb + e * 256 + ((cb * 2) ^ ((e & 7) << 4))) = hv;
    }
}

struct Ptrs {
  u16* wpk; u16* xnT; u16* flux;
  int* offsI; int* offsJ; int* listI; int* listJ; int* headI; int* headJ;
};

__global__ __launch_bounds__(256) void detect_kernel(const u16* __restrict__ xn, int* flag) {
  __shared__ int cnt;
  if (threadIdx.x == 0) cnt = 0;
  __syncthreads();
  int ok = 0;
  for (int i = threadIdx.x; i < 512; i += 256) {
    u16 v = xn[i];
    int e = (v >> 7) & 0xFF;
    if (v == 0 || (e >= 117 && e <= 130)) ok++;
  }
  atomicAdd(&cnt, ok);
  __syncthreads();
  if (threadIdx.x == 0) *flag = (cnt >= 480) ? 1 : 0;
}

struct RepackDesc { const void* src; size_t srcOff; size_t dstOff; int rows; int K; };
struct RepackArgs { RepackDesc d[21]; };
__global__ __launch_bounds__(256) void repack_kernel(RepackArgs a, Ptrs pa, Ptrs pb,
                                                     const int* flag) {
  int fl = *flag;
  Ptrs P = fl ? pa : pb;
  RepackDesc d = a.d[blockIdx.y];
  int Kd8 = d.K >> 3;
  int nch = d.rows * Kd8;
  int c = blockIdx.x * 256 + threadIdx.x;
  if (c >= nch) return;
  int row = c / Kd8;
  int kb = c - row * Kd8;
  u16x8 v;
  if (fl) {
    v = *(const u16x8*)((const u16*)d.src + d.srcOff + (size_t)row * d.K + kb * 8);
  } else {
    const float* s = (const float*)d.src + d.srcOff + (size_t)row * d.K + kb * 8;
    f32x4 f0 = *(const f32x4*)s;
    f32x4 f1 = *(const f32x4*)(s + 4);
    for (int j = 0; j < 4; ++j) { v[j] = f2bf(f0[j]); v[4 + j] = f2bf(f1[j]); }
  }
  *(u16x8*)(P.wpk + d.dstOff + (((size_t)((row >> 4) * Kd8 + kb)) << 7) + ((row & 15) << 3)) = v;
}

// ---------------- CSR build ----------------
__global__ __launch_bounds__(256) void csr_zero_kernel(Ptrs pa, Ptrs pb, const int* flag, int N) {
  Ptrs P = *flag ? pa : pb;
  int i = blockIdx.x * 256 + threadIdx.x;
  if (i < N) { P.headI[i] = 0; P.headJ[i] = 0; }
}
__global__ __launch_bounds__(256) void csr_hist_kernel(const int* __restrict__ iInd,
                                                       const int* __restrict__ jInd,
                                                       Ptrs pa, Ptrs pb, const int* flag, int E) {
  Ptrs P = *flag ? pa : pb;
  int e = blockIdx.x * 256 + threadIdx.x;
  if (e < E) {
    atomicAdd(&P.headI[iInd[e]], 1);
    atomicAdd(&P.headJ[jInd[e]], 1);
  }
}
__global__ __launch_bounds__(256) void csr_scan_kernel(Ptrs pa, Ptrs pb, const int* flag, int N) {
  Ptrs P = *flag ? pa : pb;
  __shared__ int sums[256];
  int t = threadIdx.x;
  int chunk = (N + 255) / 256;
  for (int pass = 0; pass < 2; ++pass) {
    int* cnt = pass ? P.headJ : P.headI;
    int* offs = pass ? P.offsJ : P.offsI;
    int lo = t * chunk;
    int hi = lo + chunk; if (hi > N) hi = N; if (lo > N) lo = N;
    int s = 0;
    for (int i = lo; i < hi; ++i) s += cnt[i];
    sums[t] = s;
    __syncthreads();
    if (t == 0) {
      int acc = 0;
      for (int i = 0; i < 256; ++i) { int v = sums[i]; sums[i] = acc; acc += v; }
      offs[N] = acc;
    }
    __syncthreads();
    int run = sums[t];
    for (int i = lo; i < hi; ++i) {
      int v = cnt[i];
      offs[i] = run;
      cnt[i] = run;  // head = offs for fill phase
      run += v;
    }
    __syncthreads();
  }
}
__global__ __launch_bounds__(256) void csr_fill_kernel(const int* __restrict__ iInd,
                                                       const int* __restrict__ jInd,
                                                       Ptrs pa, Ptrs pb, const int* flag, int E) {
  Ptrs P = *flag ? pa : pb;
  int e = blockIdx.x * 256 + threadIdx.x;
  if (e < E) {
    int p = atomicAdd(&P.headI[iInd[e]], 1);
    P.listI[p] = e;
    int q = atomicAdd(&P.headJ[jInd[e]], 1);
    P.listJ[q] = e;
  }
}

// ---------------- opening (TILE=32, 4 waves) ----------------
__global__ __launch_bounds__(256) void open_kernel(const void* __restrict__ xin, int M,
                                                   int isXn, u16* __restrict__ fixedDst,
                                                   size_t k1Off, size_t k2Off,
                                                   Ptrs pa, Ptrs pb, const int* flag) {
  __shared__ u16 Ush[32 * 64];
  __shared__ u16 Hsh[32 * 128];
  int fl = *flag;
  Ptrs P = fl ? pa : pb;
  u16* outT = isXn ? P.xnT : fixedDst;
  const u16* K1pk = P.wpk + k1Off;
  const u16* K2pk = P.wpk + k2Off;
  int t = threadIdx.x, w = t >> 6, l = t & 63;
  int e0 = blockIdx.x * 32;
  char* ub = (char*)Ush;
  char* hb = (char*)Hsh;
  {
    int c = t >> 3;
    int e4 = (t & 7) * 4;
    for (int it = 0; it < 2; ++it, c += 32) {
      u16 v[4] = {0, 0, 0, 0};
      if (fl) {
        const u16* xs = (const u16*)xin;
        if (e0 + e4 + 3 < M) {
          u16x4 tmp = *(const u16x4*)(xs + (size_t)c * M + e0 + e4);
          for (int j = 0; j < 4; ++j) v[j] = tmp[j];
        } else {
          for (int j = 0; j < 4; ++j)
            if (e0 + e4 + j < M) v[j] = xs[(size_t)c * M + e0 + e4 + j];
        }
      } else {
        const float* xf = (const float*)xin;
        if (e0 + e4 + 3 < M) {
          f32x4 tmp = *(const f32x4*)(xf + (size_t)c * M + e0 + e4);
          for (int j = 0; j < 4; ++j) v[j] = f2bf(tmp[j]);
        } else {
          for (int j = 0; j < 4; ++j)
            if (e0 + e4 + j < M) v[j] = f2bf(xf[(size_t)c * M + e0 + e4 + j]);
        }
      }
      for (int j = 0; j < 4; ++j) {
        int e = e4 + j;
        *(u16*)(ub + e * 128 + ((c * 2) ^ ((e & 7) << 4))) = v[j];
      }
    }
  }
  __syncthreads();
  f32x4 acc[2][2] = {};
  gemm2x2(K1pk, ub, 64, 128, w, l, acc);
  tanh_to_H(hb, w, l, acc);
  __syncthreads();
  f32x4 acc2[2][2] = {};
  gemm2x2(K2pk, hb, 128, 256, w, l, acc2);
  for (int mi = 0; mi < 2; ++mi)
    for (int ni = 0; ni < 2; ++ni) {
      int e = 16 * ni + (l & 15);
      if (e0 + e < M) {
        int cb = w * 32 + 16 * mi + ((l >> 4) << 2);
        u16x4 o;
        for (int r = 0; r < 4; ++r) o[r] = f2bf(acc2[mi][ni][r]);
        *(u16x4*)(outT + (size_t)(e0 + e) * 128 + cb) = o;
      }
    }
}

// ---------------- fused edge layer: TILE=64 edges, 8 waves (4 row x 2 col) ----------------
__global__ __launch_bounds__(512) void edge_kernel(u16* __restrict__ xeT,
                                                   const int* __restrict__ iInd,
                                                   const int* __restrict__ jInd,
                                                   size_t e1Off, size_t e2Off, int E,
                                                   Ptrs pa, Ptrs pb, const int* flag) {
  __shared__ u16 Ush[64 * 384];
  __shared__ u16 Hsh[64 * 128];
  __shared__ int sI[64], sJ[64];
  Ptrs P = *flag ? pa : pb;
  const u16* xnT = P.xnT;
  const u16* E1pk = P.wpk + e1Off;
  const u16* E2pk = P.wpk + e2Off;
  int t = threadIdx.x, w = t >> 6, l = t & 63;
  int wr = w >> 1, wc = w & 1;
  int e0 = blockIdx.x * 64;
  char* ub = (char*)Ush;
  char* hb = (char*)Hsh;
  if (t < 64) {
    int ee = (e0 + t < E) ? e0 + t : E - 1;
    sI[t] = iInd[ee];
    sJ[t] = jInd[ee];
  }
  __syncthreads();
  for (int it = 0; it < 2; ++it) {
    int chunk = t + it * 512;
    int e = chunk >> 4, c = (chunk & 15) * 8;
    int ni = sI[e], nj = sJ[e];
    u16x8 xi = *(const u16x8*)(xnT + (size_t)ni * 128 + c);
    u16x8 xj = *(const u16x8*)(xnT + (size_t)nj * 128 + c);
    int eg = (e0 + e < E) ? e0 + e : E - 1;
    u16x8 xe = *(const u16x8*)(xeT + (size_t)eg * 128 + c);
    u16x8 iv, gv;
    for (int k = 0; k < 8; ++k) {
      float a = bf2f(xi[k]), b = bf2f(xj[k]);
      iv[k] = f2bf(0.5f * (a + b));
      gv[k] = f2bf(a - b);
    }
    *(u16x8*)(ub + e * 768 + ((c * 2) ^ ((e & 7) << 4))) = iv;
    *(u16x8*)(ub + e * 768 + (((128 + c) * 2) ^ ((e & 7) << 4))) = xe;
    *(u16x8*)(ub + e * 768 + (((256 + c) * 2) ^ ((e & 7) << 4))) = gv;
  }
  __syncthreads();
  char* ubw = ub + wc * 32 * 768;   // this wave's 32 edge columns
  char* hbw = hb + wc * 32 * 256;
  f32x4 acc[2][2] = {};
  gemm2x2(E1pk, ubw, 384, 768, wr, l, acc);
  tanh_to_H(hbw, wr, l, acc);
  __syncthreads();
  f32x4 acc2[2][2] = {};
  gemm2x2(E2pk, hbw, 128, 256, wr, l, acc2);
  for (int mi = 0; mi < 2; ++mi)
    for (int ni = 0; ni < 2; ++ni) {
      int el = wc * 32 + 16 * ni + (l & 15);
      int e = e0 + el;
      if (e < E) {
        int cb = wr * 32 + 16 * mi + ((l >> 4) << 2);
        f32x4 v = acc2[mi][ni];
        u16x4 fb;
        for (int r = 0; r < 4; ++r) fb[r] = f2bf(v[r]);
        *(u16x4*)(P.flux + (size_t)e * 128 + cb) = fb;
        u16x4 old = *(u16x4*)(ub + el * 768 + (((128 + cb) * 2) ^ ((el & 7) << 4)));
        u16x4 nv;
        for (int r = 0; r < 4; ++r) nv[r] = f2bf(bf2f(old[r]) - 0.1f * v[r]);
        *(u16x4*)(xeT + (size_t)e * 128 + cb) = nv;
      }
    }
}

// ---------------- fused node layer: 512 thr, 16 thr/node gather, 8-wave 1x2 GEMM ----------------
__global__ __launch_bounds__(512) void node_kernel(size_t n1Off, size_t n2Off, int N,
                                                   Ptrs pa, Ptrs pb, const int* flag) {
  __shared__ u16 Ush[32 * 384];
  __shared__ u16 Hsh[32 * 128];
  Ptrs P = *flag ? pa : pb;
  u16* xnT = P.xnT;
  const u16* N1pk = P.wpk + n1Off;
  const u16* N2pk = P.wpk + n2Off;
  int t = threadIdx.x, w = t >> 6, l = t & 63;
  int n0 = blockIdx.x * 32;
  char* ub = (char*)Ush;
  char* hb = (char*)Hsh;
  // gather: 16 threads per node, 8 channels each
  int nl = t >> 4, c8 = (t & 15) * 8;
  int n = n0 + nl;
  float ai[8], aj[8];
#pragma unroll
  for (int k = 0; k < 8; ++k) { ai[k] = 0.f; aj[k] = 0.f; }
  u16x8 xr = {0, 0, 0, 0, 0, 0, 0, 0};
  if (n < N) {
    const u16* fx = P.flux;
    {
      int p = P.offsI[n], pe = P.offsI[n + 1];
      for (; p + 1 < pe; p += 2) {
        int ea = P.listI[p], eb = P.listI[p + 1];
        u16x8 a0 = *(const u16x8*)(fx + (size_t)ea * 128 + c8);
        u16x8 b0 = *(const u16x8*)(fx + (size_t)eb * 128 + c8);
#pragma unroll
        for (int k = 0; k < 8; ++k) ai[k] += bf2f(a0[k]) + bf2f(b0[k]);
      }
      if (p < pe) {
        int ea = P.listI[p];
        u16x8 a0 = *(const u16x8*)(fx + (size_t)ea * 128 + c8);
#pragma unroll
        for (int k = 0; k < 8; ++k) ai[k] += bf2f(a0[k]);
      }
    }
    {
      int p = P.offsJ[n], pe = P.offsJ[n + 1];
      for (; p + 1 < pe; p += 2) {
        int ea = P.listJ[p], eb = P.listJ[p + 1];
        u16x8 a0 = *(const u16x8*)(fx + (size_t)ea * 128 + c8);
        u16x8 b0 = *(const u16x8*)(fx + (size_t)eb * 128 + c8);
#pragma unroll
        for (int k = 0; k < 8; ++k) aj[k] += bf2f(a0[k]) + bf2f(b0[k]);
      }
      if (p < pe) {
        int ea = P.listJ[p];
        u16x8 a0 = *(const u16x8*)(fx + (size_t)ea * 128 + c8);
#pragma unroll
        for (int k = 0; k < 8; ++k) aj[k] += bf2f(a0[k]);
      }
    }
    xr = *(const u16x8*)(xnT + (size_t)n * 128 + c8);
  }
  u16x8 av, dv;
#pragma unroll
  for (int k = 0; k < 8; ++k) {
    av[k] = f2bf(0.5f * (ai[k] + aj[k]));
    dv[k] = f2bf(ai[k] - aj[k]);
  }
  int sw = (nl & 7) << 4;
  *(u16x8*)(ub + nl * 768 + ((c8 * 2) ^ sw)) = av;
  *(u16x8*)(ub + nl * 768 + (((128 + c8) * 2) ^ sw)) = dv;
  *(u16x8*)(ub + nl * 768 + (((256 + c8) * 2) ^ sw)) = xr;
  __syncthreads();
  // GEMM1: wave w -> out rows [16w,16w+16), cols = 32 nodes
  f32x4 acc[2] = {};
  for (int ks = 0; ks < 384; ks += 32) {
    u16x8 a = ldApk(N1pk, 48, w, ks, l);
    int kbyte = (ks + ((l >> 4) << 3)) << 1;
    u16x8 b0 = ldsB(ub, 768, l & 15, kbyte);
    u16x8 b1 = ldsB(ub, 768, 16 + (l & 15), kbyte);
    acc[0] = MFMA(a, b0, acc[0]);
    acc[1] = MFMA(a, b1, acc[1]);
  }
  for (int ni = 0; ni < 2; ++ni) {
    int e = 16 * ni + (l & 15);
    int cb = 16 * w + ((l >> 4) << 2);
    u16x4 hv;
    for (int r = 0; r < 4; ++r) hv[r] = f2bf(tanhf(acc[ni][r]));
    *(u16x4*)(hb + e * 256 + ((cb * 2) ^ ((e & 7) << 4))) = hv;
  }
  __syncthreads();
  f32x4 acc2[2] = {};
  for (int ks = 0; ks < 128; ks += 32) {
    u16x8 a = ldApk(N2pk, 16, w, ks, l);
    int kbyte = (ks + ((l >> 4) << 3)) << 1;
    u16x8 b0 = ldsB(hb, 256, l & 15, kbyte);
    u16x8 b1 = ldsB(hb, 256, 16 + (l & 15), kbyte);
    acc2[0] = MFMA(a, b0, acc2[0]);
    acc2[1] = MFMA(a, b1, acc2[1]);
  }
  for (int ni = 0; ni < 2; ++ni) {
    int nn = 16 * ni + (l & 15);
    int ng = n0 + nn;
    if (ng < N) {
      int cb = 16 * w + ((l >> 4) << 2);
      u16x4 old = *(u16x4*)(ub + nn * 768 + (((256 + cb) * 2) ^ ((nn & 7) << 4)));
      u16x4 nv;
      for (int r = 0; r < 4; ++r) nv[r] = f2bf(bf2f(old[r]) - 0.1f * acc2[ni][r]);
      *(u16x4*)(xnT + (size_t)ng * 128 + cb) = nv;
    }
  }
}

// ---------------- close ----------------
__global__ __launch_bounds__(256) void close_kernel(size_t kcOff, int Nn, char* outb,
                                                    Ptrs pa, Ptrs pb, const int* flag) {
  int fl = *flag;
  Ptrs P = fl ? pa : pb;
  const u16* xnT = P.xnT;
  const u16* KCpk = P.wpk + kcOff;
  int t = threadIdx.x, w = t >> 6, l = t & 63;
  int n0 = blockIdx.x * 64 + w * 16;
  f32x4 acc[4] = {};
  int nr = n0 + (l & 15);
  if (nr > Nn - 1) nr = Nn - 1;
  for (int ks = 0; ks < 128; ks += 32) {
    u16x8 a = *(const u16x8*)(xnT + (size_t)nr * 128 + ks + ((l >> 4) << 3));
    for (int ci = 0; ci < 4; ++ci) {
      u16x8 b = ldApk(KCpk, 16, ci, ks, l);
      acc[ci] = MFMA(a, b, acc[ci]);
    }
  }
  for (int ci = 0; ci < 4; ++ci) {
    int c = 16 * ci + (l & 15);
    int nb = n0 + ((l >> 4) << 2);
    if (fl) {
      u16* o16 = (u16*)outb;
      u16x4 o;
      for (int r = 0; r < 4; ++r) o[r] = f2bf(acc[ci][r]);
      if (nb + 3 < Nn) *(u16x4*)(o16 + (size_t)c * Nn + nb) = o;
      else
        for (int r = 0; r < 4; ++r)
          if (nb + r < Nn) o16[(size_t)c * Nn + nb + r] = o[r];
    } else {
      float* of = (float*)outb;
      if (nb + 3 < Nn) *(f32x4*)(of + (size_t)c * Nn + nb) = acc[ci];
      else
        for (int r = 0; r < 4; ++r)
          if (nb + r < Nn) of[(size_t)c * Nn + nb + r] = acc[ci][r];
    }
  }
}

// ---------------- final xe transpose ----------------
__global__ __launch_bounds__(256) void xe_out_kernel(const u16* __restrict__ xeT, int E, int Nn,
                                                     char* outb, const int* flag) {
  __shared__ u16 T[32][136];
  int fl = *flag;
  int t = threadIdx.x;
  int e0 = blockIdx.x * 32;
  for (int it = 0; it < 2; ++it) {
    int chunk = t + it * 256;
    int e = chunk >> 4, cb = (chunk & 15) * 8;
    int eg = (e0 + e < E) ? e0 + e : E - 1;
    u16x8 v = *(const u16x8*)(xeT + (size_t)eg * 128 + cb);
    for (int j = 0; j < 8; ++j) T[e][cb + j] = v[j];
  }
  __syncthreads();
  int c = t >> 1;
  int eb = (t & 1) * 16;
  if (fl) {
    u16* o16 = (u16*)outb + (size_t)64 * Nn;
    if (e0 + eb + 15 < E) {
      u16x8 o0, o1;
      for (int k = 0; k < 8; ++k) { o0[k] = T[eb + k][c]; o1[k] = T[eb + 8 + k][c]; }
      *(u16x8*)(o16 + (size_t)c * E + e0 + eb) = o0;
      *(u16x8*)(o16 + (size_t)c * E + e0 + eb + 8) = o1;
    } else {
      for (int k = 0; k < 16; ++k) {
        int e = e0 + eb + k;
        if (e < E) o16[(size_t)c * E + e] = T[eb + k][c];
      }
    }
  } else {
    float* of = (float*)outb + (size_t)64 * Nn;
    if (e0 + eb + 15 < E) {
      for (int q = 0; q < 4; ++q) {
        f32x4 o;
        for (int k = 0; k < 4; ++k) o[k] = bf2f(T[eb + q * 4 + k][c]);
        *(f32x4*)(of + (size_t)c * E + e0 + eb + q * 4) = o;
      }
    } else {
      for (int k = 0; k < 16; ++k) {
        int e = e0 + eb + k;
        if (e < E) of[(size_t)c * E + e] = bf2f(T[eb + k][c]);
      }
    }
  }
}

extern "C" void kernel_launch(void* const* d_in, const int* in_sizes, int n_in,
                              void* d_out, int out_size, void* d_ws, size_t ws_size,
                              hipStream_t stream) {
  const void* xn_in = d_in[0];
  const void* xe_in = d_in[1];
  const int* iInd = (const int*)d_in[2];
  const int* jInd = (const int*)d_in[3];

  int N = in_sizes[0] / 64;
  int E = in_sizes[2];
  int NP = (N + 31) & ~31;

  u16* xeT = (u16*)d_ws;                                   // E*256 bytes
  int* flag = (int*)((char*)d_ws + (size_t)E * 256);

  const size_t WPK_ELEMS = 581632;                         // packed weights, u16
  const size_t TAILB = WPK_ELEMS * 2 + (size_t)NP * 256;   // wpk + xnT bytes
  char* outb = (char*)d_out;

  auto buildCsrFlux = [&](Ptrs& P, char* base, size_t o) {
    P.flux = (u16*)(base + o); o += (size_t)E * 256;
    P.offsI = (int*)(base + o); o += (size_t)(N + 1) * 4;
    P.offsJ = (int*)(base + o); o += (size_t)(N + 1) * 4;
    P.listI = (int*)(base + o); o += (size_t)E * 4;
    P.listJ = (int*)(base + o); o += (size_t)E * 4;
    P.headI = (int*)(base + o); o += (size_t)N * 4;
    P.headJ = (int*)(base + o);
  };

  // fp32 path (expected): flux+CSR in d_out middle (dead until epilogue);
  // wpk+xnT at d_out tail. xn region [0, 64N*4) written only by close (last).
  Ptrs pb;
  {
    size_t tail = (((size_t)out_size * 4) - TAILB) & ~(size_t)255;
    pb.wpk = (u16*)(outb + tail);
    pb.xnT = pb.wpk + WPK_ELEMS;
    size_t o = ((size_t)64 * N * 4 + 255) & ~(size_t)255;
    buildCsrFlux(pb, outb, o);
  }
  // bf16 path (defensive only): flux+CSR in ws after xeT; tail of (bf16) d_out.
  Ptrs pa;
  {
    size_t tail = (((size_t)out_size * 2) - TAILB) & ~(size_t)255;
    pa.wpk = (u16*)(outb + tail);
    pa.xnT = pa.wpk + WPK_ELEMS;
    size_t o = ((size_t)E * 256 + 256 + 255) & ~(size_t)255;
    buildCsrFlux(pa, (char*)d_ws, o);
  }

  size_t woff[21];
  {
    size_t p = 0;
    auto nxt = [&](int i, size_t sz) { woff[i] = p; p += sz; };
    nxt(0, 128 * 64);
    nxt(1, 128 * 128);
    nxt(2, 128 * 64);
    nxt(3, 128 * 128);
    nxt(4, 64 * 128);
    for (int i = 0; i < 4; ++i) nxt(5 + i, 128 * 384);
    for (int i = 0; i < 4; ++i) nxt(9 + i, 128 * 128);
    for (int i = 0; i < 4; ++i) nxt(13 + i, 128 * 384);
    for (int i = 0; i < 4; ++i) nxt(17 + i, 128 * 128);
  }

  RepackArgs ra;
  auto setd = [&](int idx, const void* src, size_t srcOff, int rows, int K) {
    ra.d[idx].src = src;
    ra.d[idx].srcOff = srcOff;
    ra.d[idx].dstOff = woff[idx];
    ra.d[idx].rows = rows;
    ra.d[idx].K = K;
  };
  setd(0, d_in[5], 0, 128, 64);
  setd(1, d_in[6], 0, 128, 128);
  setd(2, d_in[7], 0, 128, 64);
  setd(3, d_in[8], 0, 128, 128);
  setd(4, d_in[9], 0, 64, 128);
  for (int i = 0; i < 4; ++i) setd(5 + i, d_in[10], (size_t)i * 128 * 384, 128, 384);
  for (int i = 0; i < 4; ++i) setd(9 + i, d_in[11], (size_t)i * 128 * 128, 128, 128);
  for (int i = 0; i < 4; ++i) setd(13 + i, d_in[12], (size_t)i * 128 * 384, 128, 384);
  for (int i = 0; i < 4; ++i) setd(17 + i, d_in[13], (size_t)i * 128 * 128, 128, 128);

  detect_kernel<<<1, 256, 0, stream>>>((const u16*)xn_in, flag);
  repack_kernel<<<dim3(24, 21), 256, 0, stream>>>(ra, pa, pb, flag);

  csr_zero_kernel<<<(N + 255) / 256, 256, 0, stream>>>(pa, pb, flag, N);
  csr_hist_kernel<<<(E + 255) / 256, 256, 0, stream>>>(iInd, jInd, pa, pb, flag, E);
  csr_scan_kernel<<<1, 256, 0, stream>>>(pa, pb, flag, N);
  csr_fill_kernel<<<(E + 255) / 256, 256, 0, stream>>>(iInd, jInd, pa, pb, flag, E);

  open_kernel<<<(N + 31) / 32, 256, 0, stream>>>(xn_in, N, 1, (u16*)nullptr,
                                                 woff[0], woff[1], pa, pb, flag);
  open_kernel<<<(E + 31) / 32, 256, 0, stream>>>(xe_in, E, 0, xeT,
                                                 woff[2], woff[3], pa, pb, flag);

  for (int i = 0; i < 4; ++i) {
    edge_kernel<<<(E + 63) / 64, 512, 0, stream>>>(xeT, iInd, jInd, woff[5 + i], woff[9 + i], E,
                                                   pa, pb, flag);
    node_kernel<<<(N + 31) / 32, 512, 0, stream>>>(woff[13 + i], woff[17 + i], N, pa, pb, flag);
  }

  close_kernel<<<(N + 63) / 64, 256, 0, stream>>>(woff[4], N, outb, pa, pb, flag);
  xe_out_kernel<<<(E + 31) / 32, 256, 0, stream>>>(xeT, E, N, outb, flag);
}

// Round 9
// 648.604 us; speedup vs baseline: 1.0357x; 1.0357x over previous
//
#include <hip/hip_runtime.h>

typedef unsigned short u16;
typedef __attribute__((ext_vector_type(4))) unsigned short u16x4;
typedef __attribute__((ext_vector_type(8))) unsigned short u16x8;
typedef __attribute__((ext_vector_type(4))) float f32x4;
typedef __attribute__((ext_vector_type(8))) __bf16 b16x8;

__device__ __forceinline__ float bf2f(u16 u) {
  unsigned x = ((unsigned)u) << 16;
  return __builtin_bit_cast(float, x);
}
__device__ __forceinline__ u16 f2bf(float f) {
  unsigned u = __builtin_bit_cast(unsigned, f);
  u += 0x7fffu + ((u >> 16) & 1u);
  return (u16)(u >> 16);
}
// tanh via hw exp+rcp: ~6 VALU ops vs ~25 for libcall tanhf. NaN-free at +-inf.
__device__ __forceinline__ float fast_tanh(float x) {
  float t = __expf(2.0f * x);
  return 1.0f - 2.0f * __builtin_amdgcn_rcpf(t + 1.0f);
}
__device__ __forceinline__ f32x4 MFMA(u16x8 a, u16x8 b, f32x4 c) {
  return __builtin_amdgcn_mfma_f32_16x16x32_bf16(
      __builtin_bit_cast(b16x8, a), __builtin_bit_cast(b16x8, b), c, 0, 0, 0);
}
__device__ __forceinline__ u16x8 ldApk(const u16* __restrict__ Apk, int Kdiv8, int rb, int ks, int l) {
  int kb = (ks >> 3) + (l >> 4);
  return *(const u16x8*)(Apk + (((size_t)(rb * Kdiv8 + kb)) << 7) + ((l & 15) << 3));
}
__device__ __forceinline__ u16x8 ldsB(const char* base, int rowB, int e, int kbyte) {
  return *(const u16x8*)(base + e * rowB + (kbyte ^ ((e & 7) << 4)));
}

// wave computes 32 out rows (rb0=2w), 32 cols (edges 0..31 relative to Bb base)
__device__ __forceinline__ void gemm2x2(const u16* __restrict__ Apk, const char* Bb,
                                        int K, int rowB, int w, int l, f32x4 acc[2][2]) {
  int Kd8 = K >> 3;
  int rb0 = w * 2;
  for (int ks = 0; ks < K; ks += 32) {
    u16x8 a0 = ldApk(Apk, Kd8, rb0, ks, l);
    u16x8 a1 = ldApk(Apk, Kd8, rb0 + 1, ks, l);
    int kbyte = (ks + ((l >> 4) << 3)) << 1;
    u16x8 b0 = ldsB(Bb, rowB, l & 15, kbyte);
    u16x8 b1 = ldsB(Bb, rowB, 16 + (l & 15), kbyte);
    acc[0][0] = MFMA(a0, b0, acc[0][0]);
    acc[0][1] = MFMA(a0, b1, acc[0][1]);
    acc[1][0] = MFMA(a1, b0, acc[1][0]);
    acc[1][1] = MFMA(a1, b1, acc[1][1]);
  }
}

__device__ __forceinline__ void tanh_to_H(char* hb, int w, int l, f32x4 acc[2][2]) {
  for (int mi = 0; mi < 2; ++mi)
    for (int ni = 0; ni < 2; ++ni) {
      int e = 16 * ni + (l & 15);
      int cb = w * 32 + 16 * mi + ((l >> 4) << 2);
      u16x4 hv;
      for (int r = 0; r < 4; ++r) hv[r] = f2bf(fast_tanh(acc[mi][ni][r]));
      *(u16x4*)(hb + e * 256 + ((cb * 2) ^ ((e & 7) << 4))) = hv;
    }
}

struct Ptrs {
  u16* wpk; u16* xnT; u16* flux;
  int* offsI; int* offsJ; int* listI; int* listJ; int* headI; int* headJ;
};

__global__ __launch_bounds__(256) void detect_kernel(const u16* __restrict__ xn, int* flag) {
  __shared__ int cnt;
  if (threadIdx.x == 0) cnt = 0;
  __syncthreads();
  int ok = 0;
  for (int i = threadIdx.x; i < 512; i += 256) {
    u16 v = xn[i];
    int e = (v >> 7) & 0xFF;
    if (v == 0 || (e >= 117 && e <= 130)) ok++;
  }
  atomicAdd(&cnt, ok);
  __syncthreads();
  if (threadIdx.x == 0) *flag = (cnt >= 480) ? 1 : 0;
}

struct RepackDesc { const void* src; size_t srcOff; size_t dstOff; int rows; int K; };
struct RepackArgs { RepackDesc d[21]; };
__global__ __launch_bounds__(256) void repack_kernel(RepackArgs a, Ptrs pa, Ptrs pb,
                                                     const int* flag) {
  int fl = *flag;
  Ptrs P = fl ? pa : pb;
  RepackDesc d = a.d[blockIdx.y];
  int Kd8 = d.K >> 3;
  int nch = d.rows * Kd8;
  int c = blockIdx.x * 256 + threadIdx.x;
  if (c >= nch) return;
  int row = c / Kd8;
  int kb = c - row * Kd8;
  u16x8 v;
  if (fl) {
    v = *(const u16x8*)((const u16*)d.src + d.srcOff + (size_t)row * d.K + kb * 8);
  } else {
    const float* s = (const float*)d.src + d.srcOff + (size_t)row * d.K + kb * 8;
    f32x4 f0 = *(const f32x4*)s;
    f32x4 f1 = *(const f32x4*)(s + 4);
    for (int j = 0; j < 4; ++j) { v[j] = f2bf(f0[j]); v[4 + j] = f2bf(f1[j]); }
  }
  *(u16x8*)(P.wpk + d.dstOff + (((size_t)((row >> 4) * Kd8 + kb)) << 7) + ((row & 15) << 3)) = v;
}

// ---------------- CSR build ----------------
__global__ __launch_bounds__(256) void csr_zero_kernel(Ptrs pa, Ptrs pb, const int* flag, int N) {
  Ptrs P = *flag ? pa : pb;
  int i = blockIdx.x * 256 + threadIdx.x;
  if (i < N) { P.headI[i] = 0; P.headJ[i] = 0; }
}
__global__ __launch_bounds__(256) void csr_hist_kernel(const int* __restrict__ iInd,
                                                       const int* __restrict__ jInd,
                                                       Ptrs pa, Ptrs pb, const int* flag, int E) {
  Ptrs P = *flag ? pa : pb;
  int e = blockIdx.x * 256 + threadIdx.x;
  if (e < E) {
    atomicAdd(&P.headI[iInd[e]], 1);
    atomicAdd(&P.headJ[jInd[e]], 1);
  }
}
__global__ __launch_bounds__(256) void csr_scan_kernel(Ptrs pa, Ptrs pb, const int* flag, int N) {
  Ptrs P = *flag ? pa : pb;
  __shared__ int sums[256];
  int t = threadIdx.x;
  int chunk = (N + 255) / 256;
  for (int pass = 0; pass < 2; ++pass) {
    int* cnt = pass ? P.headJ : P.headI;
    int* offs = pass ? P.offsJ : P.offsI;
    int lo = t * chunk;
    int hi = lo + chunk; if (hi > N) hi = N; if (lo > N) lo = N;
    int s = 0;
    for (int i = lo; i < hi; ++i) s += cnt[i];
    sums[t] = s;
    __syncthreads();
    if (t == 0) {
      int acc = 0;
      for (int i = 0; i < 256; ++i) { int v = sums[i]; sums[i] = acc; acc += v; }
      offs[N] = acc;
    }
    __syncthreads();
    int run = sums[t];
    for (int i = lo; i < hi; ++i) {
      int v = cnt[i];
      offs[i] = run;
      cnt[i] = run;  // head = offs for fill phase
      run += v;
    }
    __syncthreads();
  }
}
__global__ __launch_bounds__(256) void csr_fill_kernel(const int* __restrict__ iInd,
                                                       const int* __restrict__ jInd,
                                                       Ptrs pa, Ptrs pb, const int* flag, int E) {
  Ptrs P = *flag ? pa : pb;
  int e = blockIdx.x * 256 + threadIdx.x;
  if (e < E) {
    int p = atomicAdd(&P.headI[iInd[e]], 1);
    P.listI[p] = e;
    int q = atomicAdd(&P.headJ[jInd[e]], 1);
    P.listJ[q] = e;
  }
}

// ---------------- opening (TILE=32, 4 waves) ----------------
__global__ __launch_bounds__(256) void open_kernel(const void* __restrict__ xin, int M,
                                                   int isXn, u16* __restrict__ fixedDst,
                                                   size_t k1Off, size_t k2Off,
                                                   Ptrs pa, Ptrs pb, const int* flag) {
  __shared__ u16 Ush[32 * 64];
  __shared__ u16 Hsh[32 * 128];
  int fl = *flag;
  Ptrs P = fl ? pa : pb;
  u16* outT = isXn ? P.xnT : fixedDst;
  const u16* K1pk = P.wpk + k1Off;
  const u16* K2pk = P.wpk + k2Off;
  int t = threadIdx.x, w = t >> 6, l = t & 63;
  int e0 = blockIdx.x * 32;
  char* ub = (char*)Ush;
  char* hb = (char*)Hsh;
  {
    int c = t >> 3;
    int e4 = (t & 7) * 4;
    for (int it = 0; it < 2; ++it, c += 32) {
      u16 v[4] = {0, 0, 0, 0};
      if (fl) {
        const u16* xs = (const u16*)xin;
        if (e0 + e4 + 3 < M) {
          u16x4 tmp = *(const u16x4*)(xs + (size_t)c * M + e0 + e4);
          for (int j = 0; j < 4; ++j) v[j] = tmp[j];
        } else {
          for (int j = 0; j < 4; ++j)
            if (e0 + e4 + j < M) v[j] = xs[(size_t)c * M + e0 + e4 + j];
        }
      } else {
        const float* xf = (const float*)xin;
        if (e0 + e4 + 3 < M) {
          f32x4 tmp = *(const f32x4*)(xf + (size_t)c * M + e0 + e4);
          for (int j = 0; j < 4; ++j) v[j] = f2bf(tmp[j]);
        } else {
          for (int j = 0; j < 4; ++j)
            if (e0 + e4 + j < M) v[j] = f2bf(xf[(size_t)c * M + e0 + e4 + j]);
        }
      }
      for (int j = 0; j < 4; ++j) {
        int e = e4 + j;
        *(u16*)(ub + e * 128 + ((c * 2) ^ ((e & 7) << 4))) = v[j];
      }
    }
  }
  __syncthreads();
  f32x4 acc[2][2] = {};
  gemm2x2(K1pk, ub, 64, 128, w, l, acc);
  tanh_to_H(hb, w, l, acc);
  __syncthreads();
  f32x4 acc2[2][2] = {};
  gemm2x2(K2pk, hb, 128, 256, w, l, acc2);
  for (int mi = 0; mi < 2; ++mi)
    for (int ni = 0; ni < 2; ++ni) {
      int e = 16 * ni + (l & 15);
      if (e0 + e < M) {
        int cb = w * 32 + 16 * mi + ((l >> 4) << 2);
        u16x4 o;
        for (int r = 0; r < 4; ++r) o[r] = f2bf(acc2[mi][ni][r]);
        *(u16x4*)(outT + (size_t)(e0 + e) * 128 + cb) = o;
      }
    }
}

// ---------------- fused edge layer: 2 tiles of 32 edges per block, pipelined ----------------
// LDS: single U buffer (24KB, dead after GEMM1) + H (8KB) = 32KB -> 4+ blocks/CU.
// All global sources for BOTH tiles loaded to regs up front (T14 async-stage).
__global__ __launch_bounds__(256) void edge_kernel(u16* __restrict__ xeT,
                                                   const int* __restrict__ iInd,
                                                   const int* __restrict__ jInd,
                                                   size_t e1Off, size_t e2Off, int E,
                                                   Ptrs pa, Ptrs pb, const int* flag) {
  __shared__ u16 Ush[32 * 384];
  __shared__ u16 Hsh[32 * 128];
  Ptrs P = *flag ? pa : pb;
  const u16* xnT = P.xnT;
  const u16* E1pk = P.wpk + e1Off;
  const u16* E2pk = P.wpk + e2Off;
  int t = threadIdx.x, w = t >> 6, l = t & 63;
  int e0 = blockIdx.x * 64;
  char* ub = (char*)Ush;
  char* hb = (char*)Hsh;

  // S1: issue ALL source loads for both tiles (idx loaded per-thread, no LDS/barrier)
  u16x8 xi[2][2], xj[2][2], xe[2][2];
#pragma unroll
  for (int tau = 0; tau < 2; ++tau)
#pragma unroll
    for (int it = 0; it < 2; ++it) {
      int chunk = t + it * 256;
      int e = chunk >> 4, c = (chunk & 15) * 8;
      int eg = e0 + tau * 32 + e;
      if (eg > E - 1) eg = E - 1;
      int ni = iInd[eg], nj = jInd[eg];
      xi[tau][it] = *(const u16x8*)(xnT + (size_t)ni * 128 + c);
      xj[tau][it] = *(const u16x8*)(xnT + (size_t)nj * 128 + c);
      xe[tau][it] = *(const u16x8*)(xeT + (size_t)eg * 128 + c);
    }
  // cvt + write U (tile 0)
#pragma unroll
  for (int it = 0; it < 2; ++it) {
    int chunk = t + it * 256;
    int e = chunk >> 4, c = (chunk & 15) * 8;
    u16x8 iv, gv;
    for (int k = 0; k < 8; ++k) {
      float a = bf2f(xi[0][it][k]), b = bf2f(xj[0][it][k]);
      iv[k] = f2bf(0.5f * (a + b));
      gv[k] = f2bf(a - b);
    }
    *(u16x8*)(ub + e * 768 + ((c * 2) ^ ((e & 7) << 4))) = iv;
    *(u16x8*)(ub + e * 768 + (((128 + c) * 2) ^ ((e & 7) << 4))) = xe[0][it];
    *(u16x8*)(ub + e * 768 + (((256 + c) * 2) ^ ((e & 7) << 4))) = gv;
  }
  __syncthreads();  // B1: U0 ready
  // S2: GEMM1(0) + tanh -> H
  {
    f32x4 acc[2][2] = {};
    gemm2x2(E1pk, ub, 384, 768, w, l, acc);
    tanh_to_H(hb, w, l, acc);
  }
  __syncthreads();  // B2: H0 ready, U0 dead
  // S3: write U (tile 1) into freed U buffer; prefetch old-xe(0); GEMM2(0); epilogue(0)
#pragma unroll
  for (int it = 0; it < 2; ++it) {
    int chunk = t + it * 256;
    int e = chunk >> 4, c = (chunk & 15) * 8;
    u16x8 iv, gv;
    for (int k = 0; k < 8; ++k) {
      float a = bf2f(xi[1][it][k]), b = bf2f(xj[1][it][k]);
      iv[k] = f2bf(0.5f * (a + b));
      gv[k] = f2bf(a - b);
    }
    *(u16x8*)(ub + e * 768 + ((c * 2) ^ ((e & 7) << 4))) = iv;
    *(u16x8*)(ub + e * 768 + (((128 + c) * 2) ^ ((e & 7) << 4))) = xe[1][it];
    *(u16x8*)(ub + e * 768 + (((256 + c) * 2) ^ ((e & 7) << 4))) = gv;
  }
  {
    u16x4 oldv[2][2];
#pragma unroll
    for (int mi = 0; mi < 2; ++mi)
#pragma unroll
      for (int ni = 0; ni < 2; ++ni) {
        int el = 16 * ni + (l & 15);
        int e = e0 + el;
        if (e > E - 1) e = E - 1;
        int cb = w * 32 + 16 * mi + ((l >> 4) << 2);
        oldv[mi][ni] = *(const u16x4*)(xeT + (size_t)e * 128 + cb);
      }
    f32x4 acc2[2][2] = {};
    gemm2x2(E2pk, hb, 128, 256, w, l, acc2);
#pragma unroll
    for (int mi = 0; mi < 2; ++mi)
#pragma unroll
      for (int ni = 0; ni < 2; ++ni) {
        int el = 16 * ni + (l & 15);
        int e = e0 + el;
        if (e < E) {
          int cb = w * 32 + 16 * mi + ((l >> 4) << 2);
          f32x4 v = acc2[mi][ni];
          u16x4 fb, nv;
          for (int r = 0; r < 4; ++r) fb[r] = f2bf(v[r]);
          for (int r = 0; r < 4; ++r) nv[r] = f2bf(bf2f(oldv[mi][ni][r]) - 0.1f * v[r]);
          *(u16x4*)(P.flux + (size_t)e * 128 + cb) = fb;
          *(u16x4*)(xeT + (size_t)e * 128 + cb) = nv;
        }
      }
  }
  __syncthreads();  // B3: U1 ready, H0 dead
  // S4: GEMM1(1) + tanh -> H
  {
    f32x4 acc[2][2] = {};
    gemm2x2(E1pk, ub, 384, 768, w, l, acc);
    tanh_to_H(hb, w, l, acc);
  }
  __syncthreads();  // B4: H1 ready
  // S5: old-xe(1) prefetch, GEMM2(1), epilogue(1)
  {
    int eb = e0 + 32;
    u16x4 oldv[2][2];
#pragma unroll
    for (int mi = 0; mi < 2; ++mi)
#pragma unroll
      for (int ni = 0; ni < 2; ++ni) {
        int el = 16 * ni + (l & 15);
        int e = eb + el;
        if (e > E - 1) e = E - 1;
        int cb = w * 32 + 16 * mi + ((l >> 4) << 2);
        oldv[mi][ni] = *(const u16x4*)(xeT + (size_t)e * 128 + cb);
      }
    f32x4 acc2[2][2] = {};
    gemm2x2(E2pk, hb, 128, 256, w, l, acc2);
#pragma unroll
    for (int mi = 0; mi < 2; ++mi)
#pragma unroll
      for (int ni = 0; ni < 2; ++ni) {
        int el = 16 * ni + (l & 15);
        int e = eb + el;
        if (e < E) {
          int cb = w * 32 + 16 * mi + ((l >> 4) << 2);
          f32x4 v = acc2[mi][ni];
          u16x4 fb, nv;
          for (int r = 0; r < 4; ++r) fb[r] = f2bf(v[r]);
          for (int r = 0; r < 4; ++r) nv[r] = f2bf(bf2f(oldv[mi][ni][r]) - 0.1f * v[r]);
          *(u16x4*)(P.flux + (size_t)e * 128 + cb) = fb;
          *(u16x4*)(xeT + (size_t)e * 128 + cb) = nv;
        }
      }
  }
}

// ---------------- fused node layer: 512 thr, 16 thr/node gather, 8-wave 1x2 GEMM ----------------
__global__ __launch_bounds__(512) void node_kernel(size_t n1Off, size_t n2Off, int N,
                                                   Ptrs pa, Ptrs pb, const int* flag) {
  __shared__ u16 Ush[32 * 384];
  __shared__ u16 Hsh[32 * 128];
  Ptrs P = *flag ? pa : pb;
  u16* xnT = P.xnT;
  const u16* N1pk = P.wpk + n1Off;
  const u16* N2pk = P.wpk + n2Off;
  int t = threadIdx.x, w = t >> 6, l = t & 63;
  int n0 = blockIdx.x * 32;
  char* ub = (char*)Ush;
  char* hb = (char*)Hsh;
  // gather: 16 threads per node, 8 channels each
  int nl = t >> 4, c8 = (t & 15) * 8;
  int n = n0 + nl;
  float ai[8], aj[8];
#pragma unroll
  for (int k = 0; k < 8; ++k) { ai[k] = 0.f; aj[k] = 0.f; }
  u16x8 xr = {0, 0, 0, 0, 0, 0, 0, 0};
  if (n < N) {
    const u16* fx = P.flux;
    {
      int p = P.offsI[n], pe = P.offsI[n + 1];
      for (; p + 1 < pe; p += 2) {
        int ea = P.listI[p], eb = P.listI[p + 1];
        u16x8 a0 = *(const u16x8*)(fx + (size_t)ea * 128 + c8);
        u16x8 b0 = *(const u16x8*)(fx + (size_t)eb * 128 + c8);
#pragma unroll
        for (int k = 0; k < 8; ++k) ai[k] += bf2f(a0[k]) + bf2f(b0[k]);
      }
      if (p < pe) {
        int ea = P.listI[p];
        u16x8 a0 = *(const u16x8*)(fx + (size_t)ea * 128 + c8);
#pragma unroll
        for (int k = 0; k < 8; ++k) ai[k] += bf2f(a0[k]);
      }
    }
    {
      int p = P.offsJ[n], pe = P.offsJ[n + 1];
      for (; p + 1 < pe; p += 2) {
        int ea = P.listJ[p], eb = P.listJ[p + 1];
        u16x8 a0 = *(const u16x8*)(fx + (size_t)ea * 128 + c8);
        u16x8 b0 = *(const u16x8*)(fx + (size_t)eb * 128 + c8);
#pragma unroll
        for (int k = 0; k < 8; ++k) aj[k] += bf2f(a0[k]) + bf2f(b0[k]);
      }
      if (p < pe) {
        int ea = P.listJ[p];
        u16x8 a0 = *(const u16x8*)(fx + (size_t)ea * 128 + c8);
#pragma unroll
        for (int k = 0; k < 8; ++k) aj[k] += bf2f(a0[k]);
      }
    }
    xr = *(const u16x8*)(xnT + (size_t)n * 128 + c8);
  }
  u16x8 av, dv;
#pragma unroll
  for (int k = 0; k < 8; ++k) {
    av[k] = f2bf(0.5f * (ai[k] + aj[k]));
    dv[k] = f2bf(ai[k] - aj[k]);
  }
  int sw = (nl & 7) << 4;
  *(u16x8*)(ub + nl * 768 + ((c8 * 2) ^ sw)) = av;
  *(u16x8*)(ub + nl * 768 + (((128 + c8) * 2) ^ sw)) = dv;
  *(u16x8*)(ub + nl * 768 + (((256 + c8) * 2) ^ sw)) = xr;
  __syncthreads();
  // GEMM1: wave w -> out rows [16w,16w+16), cols = 32 nodes
  f32x4 acc[2] = {};
  for (int ks = 0; ks < 384; ks += 32) {
    u16x8 a = ldApk(N1pk, 48, w, ks, l);
    int kbyte = (ks + ((l >> 4) << 3)) << 1;
    u16x8 b0 = ldsB(ub, 768, l & 15, kbyte);
    u16x8 b1 = ldsB(ub, 768, 16 + (l & 15), kbyte);
    acc[0] = MFMA(a, b0, acc[0]);
    acc[1] = MFMA(a, b1, acc[1]);
  }
  for (int ni = 0; ni < 2; ++ni) {
    int e = 16 * ni + (l & 15);
    int cb = 16 * w + ((l >> 4) << 2);
    u16x4 hv;
    for (int r = 0; r < 4; ++r) hv[r] = f2bf(fast_tanh(acc[ni][r]));
    *(u16x4*)(hb + e * 256 + ((cb * 2) ^ ((e & 7) << 4))) = hv;
  }
  __syncthreads();
  f32x4 acc2[2] = {};
  for (int ks = 0; ks < 128; ks += 32) {
    u16x8 a = ldApk(N2pk, 16, w, ks, l);
    int kbyte = (ks + ((l >> 4) << 3)) << 1;
    u16x8 b0 = ldsB(hb, 256, l & 15, kbyte);
    u16x8 b1 = ldsB(hb, 256, 16 + (l & 15), kbyte);
    acc2[0] = MFMA(a, b0, acc2[0]);
    acc2[1] = MFMA(a, b1, acc2[1]);
  }
  for (int ni = 0; ni < 2; ++ni) {
    int nn = 16 * ni + (l & 15);
    int ng = n0 + nn;
    if (ng < N) {
      int cb = 16 * w + ((l >> 4) << 2);
      u16x4 old = *(u16x4*)(ub + nn * 768 + (((256 + cb) * 2) ^ ((nn & 7) << 4)));
      u16x4 nv;
      for (int r = 0; r < 4; ++r) nv[r] = f2bf(bf2f(old[r]) - 0.1f * acc2[ni][r]);
      *(u16x4*)(xnT + (size_t)ng * 128 + cb) = nv;
    }
  }
}

// ---------------- close ----------------
__global__ __launch_bounds__(256) void close_kernel(size_t kcOff, int Nn, char* outb,
                                                    Ptrs pa, Ptrs pb, const int* flag) {
  int fl = *flag;
  Ptrs P = fl ? pa : pb;
  const u16* xnT = P.xnT;
  const u16* KCpk = P.wpk + kcOff;
  int t = threadIdx.x, w = t >> 6, l = t & 63;
  int n0 = blockIdx.x * 64 + w * 16;
  f32x4 acc[4] = {};
  int nr = n0 + (l & 15);
  if (nr > Nn - 1) nr = Nn - 1;
  for (int ks = 0; ks < 128; ks += 32) {
    u16x8 a = *(const u16x8*)(xnT + (size_t)nr * 128 + ks + ((l >> 4) << 3));
    for (int ci = 0; ci < 4; ++ci) {
      u16x8 b = ldApk(KCpk, 16, ci, ks, l);
      acc[ci] = MFMA(a, b, acc[ci]);
    }
  }
  for (int ci = 0; ci < 4; ++ci) {
    int c = 16 * ci + (l & 15);
    int nb = n0 + ((l >> 4) << 2);
    if (fl) {
      u16* o16 = (u16*)outb;
      u16x4 o;
      for (int r = 0; r < 4; ++r) o[r] = f2bf(acc[ci][r]);
      if (nb + 3 < Nn) *(u16x4*)(o16 + (size_t)c * Nn + nb) = o;
      else
        for (int r = 0; r < 4; ++r)
          if (nb + r < Nn) o16[(size_t)c * Nn + nb + r] = o[r];
    } else {
      float* of = (float*)outb;
      if (nb + 3 < Nn) *(f32x4*)(of + (size_t)c * Nn + nb) = acc[ci];
      else
        for (int r = 0; r < 4; ++r)
          if (nb + r < Nn) of[(size_t)c * Nn + nb + r] = acc[ci][r];
    }
  }
}

// ---------------- final xe transpose ----------------
__global__ __launch_bounds__(256) void xe_out_kernel(const u16* __restrict__ xeT, int E, int Nn,
                                                     char* outb, const int* flag) {
  __shared__ u16 T[32][136];
  int fl = *flag;
  int t = threadIdx.x;
  int e0 = blockIdx.x * 32;
  for (int it = 0; it < 2; ++it) {
    int chunk = t + it * 256;
    int e = chunk >> 4, cb = (chunk & 15) * 8;
    int eg = (e0 + e < E) ? e0 + e : E - 1;
    u16x8 v = *(const u16x8*)(xeT + (size_t)eg * 128 + cb);
    for (int j = 0; j < 8; ++j) T[e][cb + j] = v[j];
  }
  __syncthreads();
  int c = t >> 1;
  int eb = (t & 1) * 16;
  if (fl) {
    u16* o16 = (u16*)outb + (size_t)64 * Nn;
    if (e0 + eb + 15 < E) {
      u16x8 o0, o1;
      for (int k = 0; k < 8; ++k) { o0[k] = T[eb + k][c]; o1[k] = T[eb + 8 + k][c]; }
      *(u16x8*)(o16 + (size_t)c * E + e0 + eb) = o0;
      *(u16x8*)(o16 + (size_t)c * E + e0 + eb + 8) = o1;
    } else {
      for (int k = 0; k < 16; ++k) {
        int e = e0 + eb + k;
        if (e < E) o16[(size_t)c * E + e] = T[eb + k][c];
      }
    }
  } else {
    float* of = (float*)outb + (size_t)64 * Nn;
    if (e0 + eb + 15 < E) {
      for (int q = 0; q < 4; ++q) {
        f32x4 o;
        for (int k = 0; k < 4; ++k) o[k] = bf2f(T[eb + q * 4 + k][c]);
        *(f32x4*)(of + (size_t)c * E + e0 + eb + q * 4) = o;
      }
    } else {
      for (int k = 0; k < 16; ++k) {
        int e = e0 + eb + k;
        if (e < E) of[(size_t)c * E + e] = bf2f(T[eb + k][c]);
      }
    }
  }
}

extern "C" void kernel_launch(void* const* d_in, const int* in_sizes, int n_in,
                              void* d_out, int out_size, void* d_ws, size_t ws_size,
                              hipStream_t stream) {
  const void* xn_in = d_in[0];
  const void* xe_in = d_in[1];
  const int* iInd = (const int*)d_in[2];
  const int* jInd = (const int*)d_in[3];

  int N = in_sizes[0] / 64;
  int E = in_sizes[2];
  int NP = (N + 31) & ~31;

  u16* xeT = (u16*)d_ws;                                   // E*256 bytes
  int* flag = (int*)((char*)d_ws + (size_t)E * 256);

  const size_t WPK_ELEMS = 581632;                         // packed weights, u16
  const size_t TAILB = WPK_ELEMS * 2 + (size_t)NP * 256;   // wpk + xnT bytes
  char* outb = (char*)d_out;

  auto buildCsrFlux = [&](Ptrs& P, char* base, size_t o) {
    P.flux = (u16*)(base + o); o += (size_t)E * 256;
    P.offsI = (int*)(base + o); o += (size_t)(N + 1) * 4;
    P.offsJ = (int*)(base + o); o += (size_t)(N + 1) * 4;
    P.listI = (int*)(base + o); o += (size_t)E * 4;
    P.listJ = (int*)(base + o); o += (size_t)E * 4;
    P.headI = (int*)(base + o); o += (size_t)N * 4;
    P.headJ = (int*)(base + o);
  };

  // fp32 path (expected): flux+CSR in d_out middle (dead until epilogue);
  // wpk+xnT at d_out tail. xn region [0, 64N*4) written only by close (last).
  Ptrs pb;
  {
    size_t tail = (((size_t)out_size * 4) - TAILB) & ~(size_t)255;
    pb.wpk = (u16*)(outb + tail);
    pb.xnT = pb.wpk + WPK_ELEMS;
    size_t o = ((size_t)64 * N * 4 + 255) & ~(size_t)255;
    buildCsrFlux(pb, outb, o);
  }
  // bf16 path (defensive only): flux+CSR in ws after xeT; tail of (bf16) d_out.
  Ptrs pa;
  {
    size_t tail = (((size_t)out_size * 2) - TAILB) & ~(size_t)255;
    pa.wpk = (u16*)(outb + tail);
    pa.xnT = pa.wpk + WPK_ELEMS;
    size_t o = ((size_t)E * 256 + 256 + 255) & ~(size_t)255;
    buildCsrFlux(pa, (char*)d_ws, o);
  }

  size_t woff[21];
  {
    size_t p = 0;
    auto nxt = [&](int i, size_t sz) { woff[i] = p; p += sz; };
    nxt(0, 128 * 64);
    nxt(1, 128 * 128);
    nxt(2, 128 * 64);
    nxt(3, 128 * 128);
    nxt(4, 64 * 128);
    for (int i = 0; i < 4; ++i) nxt(5 + i, 128 * 384);
    for (int i = 0; i < 4; ++i) nxt(9 + i, 128 * 128);
    for (int i = 0; i < 4; ++i) nxt(13 + i, 128 * 384);
    for (int i = 0; i < 4; ++i) nxt(17 + i, 128 * 128);
  }

  RepackArgs ra;
  auto setd = [&](int idx, const void* src, size_t srcOff, int rows, int K) {
    ra.d[idx].src = src;
    ra.d[idx].srcOff = srcOff;
    ra.d[idx].dstOff = woff[idx];
    ra.d[idx].rows = rows;
    ra.d[idx].K = K;
  };
  setd(0, d_in[5], 0, 128, 64);
  setd(1, d_in[6], 0, 128, 128);
  setd(2, d_in[7], 0, 128, 64);
  setd(3, d_in[8], 0, 128, 128);
  setd(4, d_in[9], 0, 64, 128);
  for (int i = 0; i < 4; ++i) setd(5 + i, d_in[10], (size_t)i * 128 * 384, 128, 384);
  for (int i = 0; i < 4; ++i) setd(9 + i, d_in[11], (size_t)i * 128 * 128, 128, 128);
  for (int i = 0; i < 4; ++i) setd(13 + i, d_in[12], (size_t)i * 128 * 384, 128, 384);
  for (int i = 0; i < 4; ++i) setd(17 + i, d_in[13], (size_t)i * 128 * 128, 128, 128);

  detect_kernel<<<1, 256, 0, stream>>>((const u16*)xn_in, flag);
  repack_kernel<<<dim3(24, 21), 256, 0, stream>>>(ra, pa, pb, flag);

  csr_zero_kernel<<<(N + 255) / 256, 256, 0, stream>>>(pa, pb, flag, N);
  csr_hist_kernel<<<(E + 255) / 256, 256, 0, stream>>>(iInd, jInd, pa, pb, flag, E);
  csr_scan_kernel<<<1, 256, 0, stream>>>(pa, pb, flag, N);
  csr_fill_kernel<<<(E + 255) / 256, 256, 0, stream>>>(iInd, jInd, pa, pb, flag, E);

  open_kernel<<<(N + 31) / 32, 256, 0, stream>>>(xn_in, N, 1, (u16*)nullptr,
                                                 woff[0], woff[1], pa, pb, flag);
  open_kernel<<<(E + 31) / 32, 256, 0, stream>>>(xe_in, E, 0, xeT,
                                                 woff[2], woff[3], pa, pb, flag);

  for (int i = 0; i < 4; ++i) {
    edge_kernel<<<(E + 63) / 64, 256, 0, stream>>>(xeT, iInd, jInd, woff[5 + i], woff[9 + i], E,
                                                   pa, pb, flag);
    node_kernel<<<(N + 31) / 32, 512, 0, stream>>>(woff[13 + i], woff[17 + i], N, pa, pb, flag);
  }

  close_kernel<<<(N + 63) / 64, 256, 0, stream>>>(woff[4], N, outb, pa, pb, flag);
  xe_out_kernel<<<(E + 31) / 32, 256, 0, stream>>>(xeT, E, N, outb, flag);
}